// Round 12
// baseline (256.254 us; speedup 1.0000x reference)
//
#include <hip/hip_runtime.h>
#include <hip/hip_fp16.h>

#define BATCH 8192
#define FDIM  512
#define NTREE 64
#define NODES 63
#define ODIM  128
#define NJP   4096            // padded node-col space: c = t*64 + n (n=63 pad)
#define K2    4096            // leaf K: k = t*64 + l
#define TPG   8               // tree-pair groups (grid.y); 4 tree-pairs each

typedef _Float16 f16;
typedef _Float16 f16x2 __attribute__((ext_vector_type(2)));
typedef _Float16 f16x8 __attribute__((ext_vector_type(8)));
typedef float    f32x4 __attribute__((ext_vector_type(4)));

// ---------------- workspace layout (bytes) ----------------
#define XH_OFF   0
#define XH_SZ    ((size_t)BATCH*FDIM*2)        // 8.39 MB  x  f16 [b][f]
#define WNH_OFF  (XH_OFF + XH_SZ)
#define WNH_SZ   ((size_t)NJP*FDIM*2)          // 4.19 MB  Wn f16 [t*64+n][f]
#define WLT_OFF  (WNH_OFF + WNH_SZ)
#define WLT_SZ   ((size_t)ODIM*K2*2)           // 1.05 MB  Wl f16 [o][t*64+l]
#define PS_OFF   (WLT_OFF + WLT_SZ)
#define PS_SZ    ((size_t)TPG*BATCH*ODIM*4)    // 33.6 MB  f32 partials per tp-group
#define CNT_OFF  (PS_OFF + PS_SZ)
#define CNT_SZ   (64 * sizeof(int))            // per-rowblk arrival counters
#define WS_NEEDED (CNT_OFF + CNT_SZ)

__device__ __forceinline__ float smooth_step_f(float t) {
    float tc = fminf(fmaxf(t, -0.5f), 0.5f);
    return fmaf(tc, fmaf(-2.0f * tc, tc, 1.5f), 0.5f);
}

__device__ __forceinline__ void async16(const void* g, void* l) {
    __builtin_amdgcn_global_load_lds((__attribute__((address_space(1))) void*)g,
                                     (__attribute__((address_space(3))) void*)l,
                                     16, 0, 0);
}

// swizzled f16 offset of (row, group g) in a [rows][64] half-tile staged as 1KB/8-row chunks
__device__ __forceinline__ int sw_off(int row, int g) {
    return ((row >> 3) * 512) + (((row & 7) * 8 + (g ^ (row & 7))) * 8);
}

// ---------------- prep: all conversions in ONE launch (+ counter zeroing) ----------------
// blocks [0,4096): x fp32->f16 ; [4096,4224): Wl transpose ; [4224,4736): Wn transpose
#define XBLK 4096
#define WLBLK 128
__global__ __launch_bounds__(256)
void prep_kernel(const float* __restrict__ x, const float* __restrict__ wn,
                 const float* __restrict__ wl,
                 f16* __restrict__ xh, f16* __restrict__ wnh, f16* __restrict__ wlt,
                 int* __restrict__ cnt)
{
    __shared__ __align__(16) char smem[16640];
    const int bid = blockIdx.x;

    if (bid < XBLK) {
        if (bid == 0 && threadIdx.x < 64) cnt[threadIdx.x] = 0;   // arrival counters
        size_t i = ((size_t)bid * 256 + threadIdx.x) * 4;
        float4 v = *(const float4*)(x + i);
        f16* o = xh + i;
        o[0] = (f16)v.x; o[1] = (f16)v.y; o[2] = (f16)v.z; o[3] = (f16)v.w;
        return;
    }
    if (bid < XBLK + WLBLK) {
        // Wl[l][o][t] fp32 -> wlt[o][t*64+l] f16 ; one block per o
        f16 (*tile)[72] = (f16(*)[72])smem;    // [t][l]
        const int o    = bid - XBLK;
        const int lane = threadIdx.x & 63;     // t on read
        const int w    = threadIdx.x >> 6;
        #pragma unroll
        for (int lc = 0; lc < 16; ++lc) {
            int l = w * 16 + lc;
            tile[lane][l] = (f16)wl[(size_t)l * (ODIM * NTREE) + o * 64 + lane];
        }
        __syncthreads();
        f16* orow = wlt + (size_t)o * K2;
        #pragma unroll
        for (int c = 0; c < 2; ++c) {
            int idx = (threadIdx.x * 2 + c) * 8;
            int t = idx >> 6, l = idx & 63;
            f16x8 v;
            #pragma unroll
            for (int e = 0; e < 8; ++e) v[e] = tile[t][l + e];
            *(f16x8*)(orow + idx) = v;
        }
        return;
    }
    // Wn[n][f][t] fp32 -> wnh[(t*64+n)][f] f16 ; n==63 zeros pad rows
    {
        const int id   = bid - (XBLK + WLBLK);   // 0..511
        const int n    = id & 63;                // 0..63 (63 = pad)
        const int f0   = (id >> 6) * 64;         // 8 f-tiles
        const int lane = threadIdx.x & 63;
        const int w    = threadIdx.x >> 6;
        if (n == NODES) {
            #pragma unroll
            for (int tc = 0; tc < 16; ++tc) {
                int t = w * 16 + tc;
                wnh[(size_t)(t * 64 + NODES) * FDIM + f0 + lane] = (f16)0.0f;
            }
            return;
        }
        float (*tile)[65] = (float(*)[65])smem;
        const float* src = wn + (size_t)n * (FDIM * NTREE);
        #pragma unroll
        for (int i = 0; i < 16; ++i) {
            int fl = w * 16 + i;
            tile[fl][lane] = src[(size_t)(f0 + fl) * NTREE + lane];
        }
        __syncthreads();
        #pragma unroll
        for (int i = 0; i < 16; ++i) {
            int t = w * 16 + i;
            wnh[(size_t)(t * 64 + n) * FDIM + f0 + lane] = (f16)tile[lane][t];
        }
    }
}

// ---------------- fused: node GEMM (BK=128) + smooth_step + fold + leaf GEMM + tail reduce ----
// grid (64 rowblks, 8 tpgroups); each block: 4 tree-pairs sequentially, lacc persistent.
// LDS map (f16 idx):
//   node loop : A staging [0,16384) (2 halves x 16 chunks), B staging [16384,32768)
//   epilogue  : gate C-tile [0,16640) stride 130 (overlays dead staging);
//               prob A-tiles [0,16384) (overlay CT after reg-read);
//               leaf B-tile [16640,33024)
__global__ __launch_bounds__(256, 2)
void fused_tree(const f16* __restrict__ xh, const f16* __restrict__ wnh,
                const float* __restrict__ bn, const f16* __restrict__ wlt,
                float* __restrict__ partial, int* __restrict__ cnt,
                float* __restrict__ outp)
{
    __shared__ f16 SH[33024];             // 66048 B
    __shared__ int sflag;
    const int tid  = threadIdx.x;
    const int lane = tid & 63;
    const int w    = tid >> 6;
    const int wm   = w & 1;
    const int wn   = w >> 1;
    const int row0 = blockIdx.x * 128;
    const int tpg  = blockIdx.y;

    const int lr = lane >> 3;
    const int lg = (lane & 7) ^ lr;
    const int frow = tid & 127;           // fold: row
    const int ftr  = tid >> 7;            // fold: tree within pair (0/1)

    f32x4 lacc[4][4] = {};                // leaf accumulator, persists over tree-pairs

    for (int tpi = 0; tpi < 4; ++tpi) {
        const int tp = tpg * 4 + tpi;
        const int j0 = tp * 128;          // node-col base (2 trees)

        // ---- node GEMM: 128 rows x 128 cols x K=512, BK=128 (4 iters) ----
        f32x4 acc[4][4] = {};
        for (int k0 = 0; k0 < FDIM; k0 += 128) {
            #pragma unroll
            for (int q = 0; q < 16; ++q) {
                int id  = w * 16 + q;          // 0..63 ; wave-uniform branch
                int isB = id >> 5;             // 0: A chunks, 1: B chunks
                int e   = id & 31;
                int h   = e >> 4, c = e & 15;
                int r   = c * 8 + lr;
                const f16* src = isB
                    ? (wnh + (size_t)(j0 + r) * FDIM + k0 + h * 64 + lg * 8)
                    : (xh  + (size_t)(row0 + r) * FDIM + k0 + h * 64 + lg * 8);
                async16(src, &SH[isB * 16384 + h * 8192 + c * 512 + lane * 8]);
            }
            __syncthreads();
            #pragma unroll
            for (int hk = 0; hk < 4; ++hk) {
                int h = hk >> 1;
                int g = (hk & 1) * 4 + (lane >> 4);
                f16x8 bfr[4];
                #pragma unroll
                for (int tn = 0; tn < 4; ++tn) {
                    int j = wn * 64 + tn * 16 + (lane & 15);
                    bfr[tn] = *(const f16x8*)&SH[16384 + h * 8192 + sw_off(j, g)];
                }
                #pragma unroll
                for (int tm = 0; tm < 4; ++tm) {
                    int m = wm * 64 + tm * 16 + (lane & 15);
                    f16x8 afr = *(const f16x8*)&SH[h * 8192 + sw_off(m, g)];
                    #pragma unroll
                    for (int tn = 0; tn < 4; ++tn)
                        acc[tm][tn] = __builtin_amdgcn_mfma_f32_16x16x32_f16(afr, bfr[tn], acc[tm][tn], 0, 0, 0);
                }
            }
            __syncthreads();
        }

        // ---- stage leaf B-tile (Wl, 128 o x 128 k) into [16640,33024) — dead region
        #pragma unroll
        for (int q = 0; q < 8; ++q) {
            int id = w * 8 + q;            // 0..31 chunks: half h, chunk c
            int h = id >> 4, c = id & 15;
            int o = c * 8 + lr;
            async16(wlt + (size_t)o * K2 + j0 + h * 64 + lg * 8,
                    &SH[16640 + h * 8192 + c * 512 + lane * 8]);
        }

        // ---- gate epilogue: bias + smooth_step -> C-tile [row][130] at base 0
        #pragma unroll
        for (int tn = 0; tn < 4; ++tn) {
            int col = wn * 64 + tn * 16 + (lane & 15);
            int nn  = col & 63;                       // node index (j0 multiple of 64)
            int tt  = (j0 + col) >> 6;                // global tree
            float bias = (nn < NODES) ? bn[nn * NTREE + tt] : 0.0f;
            #pragma unroll
            for (int tm = 0; tm < 4; ++tm) {
                #pragma unroll
                for (int r = 0; r < 4; ++r) {
                    int row = wm * 64 + tm * 16 + (lane >> 4) * 4 + r;
                    SH[row * 130 + col] = (f16)smooth_step_f(acc[tm][tn][r] + bias);
                }
            }
        }
        __syncthreads();

        // ---- fold: thread = (frow, ftr). gates contiguous, stride-130 rows (conflict-free)
        f16x8 ov[8];
        {
            const f16* gp = &SH[frow * 130 + ftr * 64];
            float g[64];
            #pragma unroll
            for (int c = 0; c < 32; ++c) {
                f16x2 v = *(const f16x2*)(gp + 2 * c);
                g[2 * c]     = (float)v[0];
                g[2 * c + 1] = (float)v[1];
            }
            float pr[32];
            pr[0] = 1.0f;
            int bse = 0;
            #pragma unroll
            for (int lvl = 0; lvl < 5; ++lvl) {
                const int width = 1 << lvl;
                #pragma unroll
                for (int i = width - 1; i >= 0; --i) {
                    float p = pr[i], s = g[bse + i];
                    pr[2 * i]     = p * s;
                    pr[2 * i + 1] = p * (1.0f - s);
                }
                bse += width;
            }
            #pragma unroll
            for (int i = 0; i < 32; ++i) {
                float s5 = g[31 + i];
                float p  = pr[i];
                ov[i >> 2][(i & 3) * 2]     = (f16)(p * s5);
                ov[i >> 2][(i & 3) * 2 + 1] = (f16)(p * (1.0f - s5));
            }
        }
        __syncthreads();   // all gate reads done before overwrite

        // ---- write prob A-tiles (chunk format) over [0,16384)
        #pragma unroll
        for (int g2 = 0; g2 < 8; ++g2)
            *(f16x8*)&SH[ftr * 8192 + sw_off(frow, g2)] = ov[g2];
        __syncthreads();   // A visible; barrier also drains vmcnt -> leaf B staged

        // ---- leaf partial GEMM: lacc += prob(128x128) * Wl^T(128x128)
        #pragma unroll
        for (int ks2 = 0; ks2 < 4; ++ks2) {
            int h  = ks2 >> 1;
            int gg = (ks2 & 1) * 4 + (lane >> 4);
            f16x8 bfr[4];
            #pragma unroll
            for (int tn = 0; tn < 4; ++tn) {
                int o = wn * 64 + tn * 16 + (lane & 15);
                bfr[tn] = *(const f16x8*)&SH[16640 + h * 8192 + sw_off(o, gg)];
            }
            #pragma unroll
            for (int tm = 0; tm < 4; ++tm) {
                int m = wm * 64 + tm * 16 + (lane & 15);
                f16x8 afr = *(const f16x8*)&SH[h * 8192 + sw_off(m, gg)];
                #pragma unroll
                for (int tn = 0; tn < 4; ++tn)
                    lacc[tm][tn] = __builtin_amdgcn_mfma_f32_16x16x32_f16(afr, bfr[tn], lacc[tm][tn], 0, 0, 0);
            }
        }
        __syncthreads();   // leaf reads done before next tree-pair's staging
    }

    // ---- write f32 partial for this tp-group (streamed, no atomics)
    float* dst = partial + (size_t)tpg * BATCH * ODIM;
    #pragma unroll
    for (int tn = 0; tn < 4; ++tn) {
        int o = wn * 64 + tn * 16 + (lane & 15);
        #pragma unroll
        for (int tm = 0; tm < 4; ++tm) {
            #pragma unroll
            for (int r = 0; r < 4; ++r) {
                int row = row0 + wm * 64 + tm * 16 + (lane >> 4) * 4 + r;
                dst[(size_t)row * ODIM + o] = lacc[tm][tn][r];
            }
        }
    }

    // ---- last arriving tp-group for this rowblk reduces the 8 partials -> out
    __threadfence();                                   // release partial writes (device scope)
    if (tid == 0) sflag = atomicAdd(&cnt[blockIdx.x], 1);
    __syncthreads();
    if (sflag == TPG - 1) {
        __threadfence();                               // acquire other blocks' partials
        #pragma unroll
        for (int it = 0; it < 16; ++it) {
            int idx = it * 256 + tid;                  // 4096 f32x4 covering 128 rows
            int row = idx >> 5, c4 = idx & 31;
            size_t off = (size_t)(row0 + row) * ODIM + c4 * 4;
            f32x4 a = *(const f32x4*)(partial + off);
            #pragma unroll
            for (int k = 1; k < TPG; ++k)
                a += *(const f32x4*)(partial + (size_t)k * BATCH * ODIM + off);
            *(f32x4*)(outp + off) = a;
        }
    }
}

// ---------------- fallback (round-1 proven kernel) ----------------
#define ROWS 8
__global__ __launch_bounds__(256, 2)
void soft_tree_fallback(const float* __restrict__ x, const float* __restrict__ Wn,
                        const float* __restrict__ bn, const float* __restrict__ Wl,
                        float* __restrict__ out)
{
    __shared__ __half s_lds[ROWS][NODES][NTREE];
    const int lane = threadIdx.x & 63;
    const int w    = threadIdx.x >> 6;
    const long row0 = (long)blockIdx.x * ROWS;
    for (int n = w; n < NODES; n += 4) {
        const float* wp = Wn + ((long)n * FDIM) * NTREE + lane;
        const float* xp = x + row0 * FDIM;
        float acc[ROWS];
        #pragma unroll
        for (int r = 0; r < ROWS; ++r) acc[r] = 0.0f;
        #pragma unroll 8
        for (int f = 0; f < FDIM; ++f) {
            float wv = wp[(long)f * NTREE];
            #pragma unroll
            for (int r = 0; r < ROWS; ++r)
                acc[r] = fmaf(xp[r * FDIM + f], wv, acc[r]);
        }
        float bias = bn[n * NTREE + lane];
        #pragma unroll
        for (int r = 0; r < ROWS; ++r)
            s_lds[r][n][lane] = __float2half(smooth_step_f(acc[r] + bias));
    }
    __syncthreads();
    const int r0 = w * 2, r1 = w * 2 + 1;
    float pr0[64], pr1[64];
    {
        pr0[0] = 1.0f; pr1[0] = 1.0f;
        int base = 0;
        #pragma unroll
        for (int lvl = 0; lvl < 6; ++lvl) {
            const int width = 1 << lvl;
            #pragma unroll
            for (int i = width - 1; i >= 0; --i) {
                float sa = __half2float(s_lds[r0][base + i][lane]);
                float sb = __half2float(s_lds[r1][base + i][lane]);
                float pa = pr0[i], pb = pr1[i];
                pr0[2 * i] = pa * sa; pr0[2 * i + 1] = pa * (1.0f - sa);
                pr1[2 * i] = pb * sb; pr1[2 * i + 1] = pb * (1.0f - sb);
            }
            base += width;
        }
    }
    for (int o = 0; o < ODIM; ++o) {
        const float* wlp = Wl + (long)o * NTREE + lane;
        float c0 = 0.0f, c1 = 0.0f;
        #pragma unroll
        for (int l = 0; l < 64; ++l) {
            float wv = wlp[(long)l * (ODIM * NTREE)];
            c0 = fmaf(pr0[l], wv, c0);
            c1 = fmaf(pr1[l], wv, c1);
        }
        #pragma unroll
        for (int off = 32; off > 0; off >>= 1) {
            c0 += __shfl_xor(c0, off, 64);
            c1 += __shfl_xor(c1, off, 64);
        }
        if (lane == 0) {
            out[(row0 + r0) * ODIM + o] = c0;
            out[(row0 + r1) * ODIM + o] = c1;
        }
    }
}

extern "C" void kernel_launch(void* const* d_in, const int* in_sizes, int n_in,
                              void* d_out, int out_size, void* d_ws, size_t ws_size,
                              hipStream_t stream) {
    const float* x  = (const float*)d_in[0];
    const float* Wn = (const float*)d_in[1];
    const float* bn = (const float*)d_in[2];
    const float* Wl = (const float*)d_in[3];
    float* out = (float*)d_out;

    if (ws_size < WS_NEEDED) {
        soft_tree_fallback<<<BATCH / ROWS, 256, 0, stream>>>(x, Wn, bn, Wl, out);
        return;
    }

    f16*   xh  = (f16*)((char*)d_ws + XH_OFF);
    f16*   wnh = (f16*)((char*)d_ws + WNH_OFF);
    f16*   wlt = (f16*)((char*)d_ws + WLT_OFF);
    float* ps  = (float*)((char*)d_ws + PS_OFF);
    int*   cnt = (int*)((char*)d_ws + CNT_OFF);

    prep_kernel<<<XBLK + WLBLK + 512, 256, 0, stream>>>(x, Wn, Wl, xh, wnh, wlt, cnt);
    fused_tree<<<dim3(BATCH / 128, TPG), 256, 0, stream>>>(xh, wnh, bn, wlt, ps, cnt, out);
}

// Round 13
// 227.079 us; speedup vs baseline: 1.1285x; 1.1285x over previous
//
#include <hip/hip_runtime.h>
#include <hip/hip_fp16.h>

#define BATCH 8192
#define FDIM  512
#define NTREE 64
#define NODES 63
#define ODIM  128
#define NJP   4096            // padded node-col space: c = t*64 + n (n=63 pad)
#define K2    4096            // leaf K: k = t*64 + l
#define TPG   8               // tree-pair groups (grid.y); 4 tree-pairs each

typedef _Float16 f16;
typedef _Float16 f16x2 __attribute__((ext_vector_type(2)));
typedef _Float16 f16x8 __attribute__((ext_vector_type(8)));
typedef float    f32x4 __attribute__((ext_vector_type(4)));

// ---------------- workspace layout (bytes) ----------------
#define XH_OFF   0
#define XH_SZ    ((size_t)BATCH*FDIM*2)        // 8.39 MB  x  f16 [b][f]
#define WNH_OFF  (XH_OFF + XH_SZ)
#define WNH_SZ   ((size_t)NJP*FDIM*2)          // 4.19 MB  Wn f16 [t*64+n][f]
#define WLT_OFF  (WNH_OFF + WNH_SZ)
#define WLT_SZ   ((size_t)ODIM*K2*2)           // 1.05 MB  Wl f16 [o][t*64+l]
#define PS_OFF   (WLT_OFF + WLT_SZ)
#define PS_SZ    ((size_t)TPG*BATCH*ODIM*4)    // 33.6 MB  f32 partials per tp-group
#define CNT_OFF  (PS_OFF + PS_SZ)
#define CNT_SZ   (64 * sizeof(int))            // per-rowblk arrival counters
#define WS_NEEDED (CNT_OFF + CNT_SZ)

__device__ __forceinline__ float smooth_step_f(float t) {
    float tc = fminf(fmaxf(t, -0.5f), 0.5f);
    return fmaf(tc, fmaf(-2.0f * tc, tc, 1.5f), 0.5f);
}

__device__ __forceinline__ void async16(const void* g, void* l) {
    __builtin_amdgcn_global_load_lds((__attribute__((address_space(1))) void*)g,
                                     (__attribute__((address_space(3))) void*)l,
                                     16, 0, 0);
}

// swizzled f16 offset of (row, group g) in a [rows][64] tile staged as 1KB/8-row chunks
__device__ __forceinline__ int sw_off(int row, int g) {
    return ((row >> 3) * 512) + (((row & 7) * 8 + (g ^ (row & 7))) * 8);
}

// ---------------- prep: all conversions in ONE launch (+ counter zeroing) ----------------
// blocks [0,4096): x fp32->f16 ; [4096,4224): Wl transpose ; [4224,4736): Wn transpose
#define XBLK 4096
#define WLBLK 128
__global__ __launch_bounds__(256)
void prep_kernel(const float* __restrict__ x, const float* __restrict__ wn,
                 const float* __restrict__ wl,
                 f16* __restrict__ xh, f16* __restrict__ wnh, f16* __restrict__ wlt,
                 int* __restrict__ cnt)
{
    __shared__ __align__(16) char smem[16640];
    const int bid = blockIdx.x;

    if (bid < XBLK) {
        if (bid == 0 && threadIdx.x < 64) cnt[threadIdx.x] = 0;   // arrival counters
        size_t i = ((size_t)bid * 256 + threadIdx.x) * 4;
        float4 v = *(const float4*)(x + i);
        f16* o = xh + i;
        o[0] = (f16)v.x; o[1] = (f16)v.y; o[2] = (f16)v.z; o[3] = (f16)v.w;
        return;
    }
    if (bid < XBLK + WLBLK) {
        // Wl[l][o][t] fp32 -> wlt[o][t*64+l] f16 ; one block per o
        f16 (*tile)[72] = (f16(*)[72])smem;    // [t][l]
        const int o    = bid - XBLK;
        const int lane = threadIdx.x & 63;     // t on read
        const int w    = threadIdx.x >> 6;
        #pragma unroll
        for (int lc = 0; lc < 16; ++lc) {
            int l = w * 16 + lc;
            tile[lane][l] = (f16)wl[(size_t)l * (ODIM * NTREE) + o * 64 + lane];
        }
        __syncthreads();
        f16* orow = wlt + (size_t)o * K2;
        #pragma unroll
        for (int c = 0; c < 2; ++c) {
            int idx = (threadIdx.x * 2 + c) * 8;
            int t = idx >> 6, l = idx & 63;
            f16x8 v;
            #pragma unroll
            for (int e = 0; e < 8; ++e) v[e] = tile[t][l + e];
            *(f16x8*)(orow + idx) = v;
        }
        return;
    }
    // Wn[n][f][t] fp32 -> wnh[(t*64+n)][f] f16 ; n==63 zeros pad rows
    {
        const int id   = bid - (XBLK + WLBLK);   // 0..511
        const int n    = id & 63;                // 0..63 (63 = pad)
        const int f0   = (id >> 6) * 64;         // 8 f-tiles
        const int lane = threadIdx.x & 63;
        const int w    = threadIdx.x >> 6;
        if (n == NODES) {
            #pragma unroll
            for (int tc = 0; tc < 16; ++tc) {
                int t = w * 16 + tc;
                wnh[(size_t)(t * 64 + NODES) * FDIM + f0 + lane] = (f16)0.0f;
            }
            return;
        }
        float (*tile)[65] = (float(*)[65])smem;
        const float* src = wn + (size_t)n * (FDIM * NTREE);
        #pragma unroll
        for (int i = 0; i < 16; ++i) {
            int fl = w * 16 + i;
            tile[fl][lane] = src[(size_t)(f0 + fl) * NTREE + lane];
        }
        __syncthreads();
        #pragma unroll
        for (int i = 0; i < 16; ++i) {
            int t = w * 16 + i;
            wnh[(size_t)(t * 64 + n) * FDIM + f0 + lane] = (f16)tile[lane][t];
        }
    }
}

// ---------------- fused: node GEMM (BK=64) + smooth_step + fold + leaf GEMM + tail reduce ----
// grid (64 rowblks, 8 tpgroups); each block: 4 tree-pairs sequentially, lacc persistent.
// LDS map (f16 idx): [0,8192) Ash / leaf-B half0 ; [8192,16384) Bsh / leaf-B half1 ;
//                    [16384, 33024) gate C-tile [128][130] -> reused as prob A-tiles (2 x 8192)
__global__ __launch_bounds__(256, 2)
void fused_tree(const f16* __restrict__ xh, const f16* __restrict__ wnh,
                const float* __restrict__ bn, const f16* __restrict__ wlt,
                float* __restrict__ partial, int* __restrict__ cnt,
                float* __restrict__ outp)
{
    __shared__ f16 SH[33024];             // 66048 B
    __shared__ int sflag;
    f16* CT = SH + 16384;                 // gate C-tile, stride 130
    const int tid  = threadIdx.x;
    const int lane = tid & 63;
    const int w    = tid >> 6;
    const int wm   = w & 1;
    const int wn   = w >> 1;
    const int row0 = blockIdx.x * 128;
    const int tpg  = blockIdx.y;

    const int lr = lane >> 3;
    const int lg = (lane & 7) ^ lr;
    const int frow = tid & 127;           // fold: row
    const int ftr  = tid >> 7;            // fold: tree within pair (0/1)

    f32x4 lacc[4][4] = {};                // leaf accumulator, persists over tree-pairs

    for (int tpi = 0; tpi < 4; ++tpi) {
        const int tp = tpg * 4 + tpi;
        const int j0 = tp * 128;          // node-col base (2 trees)

        // ---- node GEMM: 128 rows x 128 cols x K=512, BK=64 (proven round-11 loop) ----
        f32x4 acc[4][4] = {};
        for (int k0 = 0; k0 < FDIM; k0 += 64) {
            #pragma unroll
            for (int q = 0; q < 8; ++q) {
                int id = w * 8 + q;
                if (id < 16) {
                    int r = id * 8 + lr;
                    async16(xh + (size_t)(row0 + r) * FDIM + k0 + lg * 8, &SH[id * 512 + lane * 8]);
                } else {
                    int c = id - 16;
                    int r = c * 8 + lr;
                    async16(wnh + (size_t)(j0 + r) * FDIM + k0 + lg * 8, &SH[8192 + c * 512 + lane * 8]);
                }
            }
            __syncthreads();
            #pragma unroll
            for (int ks = 0; ks < 2; ++ks) {
                int g = ks * 4 + (lane >> 4);
                f16x8 bfr[4];
                #pragma unroll
                for (int tn = 0; tn < 4; ++tn) {
                    int j = wn * 64 + tn * 16 + (lane & 15);
                    bfr[tn] = *(const f16x8*)&SH[8192 + sw_off(j, g)];
                }
                #pragma unroll
                for (int tm = 0; tm < 4; ++tm) {
                    int m = wm * 64 + tm * 16 + (lane & 15);
                    f16x8 afr = *(const f16x8*)&SH[sw_off(m, g)];
                    #pragma unroll
                    for (int tn = 0; tn < 4; ++tn)
                        acc[tm][tn] = __builtin_amdgcn_mfma_f32_16x16x32_f16(afr, bfr[tn], acc[tm][tn], 0, 0, 0);
                }
            }
            __syncthreads();
        }

        // ---- stage leaf B-tile (Wl, 128 o x 128 k) into [0,32K) — free after loop barrier
        #pragma unroll
        for (int q = 0; q < 8; ++q) {
            int id = w * 8 + q;            // 0..31 chunks: half h, chunk c
            int h = id >> 4, c = id & 15;
            int o = c * 8 + lr;
            async16(wlt + (size_t)o * K2 + j0 + h * 64 + lg * 8,
                    &SH[h * 8192 + c * 512 + lane * 8]);
        }

        // ---- gate epilogue: bias + smooth_step -> C-tile [row][130]
        #pragma unroll
        for (int tn = 0; tn < 4; ++tn) {
            int col = wn * 64 + tn * 16 + (lane & 15);
            int nn  = col & 63;                       // node index (j0 multiple of 64)
            int tt  = (j0 + col) >> 6;                // global tree
            float bias = (nn < NODES) ? bn[nn * NTREE + tt] : 0.0f;
            #pragma unroll
            for (int tm = 0; tm < 4; ++tm) {
                #pragma unroll
                for (int r = 0; r < 4; ++r) {
                    int row = wm * 64 + tm * 16 + (lane >> 4) * 4 + r;
                    CT[row * 130 + col] = (f16)smooth_step_f(acc[tm][tn][r] + bias);
                }
            }
        }
        __syncthreads();

        // ---- fold: thread = (frow, ftr). gates contiguous, 2-way-free ds_read_b32
        f16x8 ov[8];
        {
            const f16* gp = &CT[frow * 130 + ftr * 64];
            float g[64];
            #pragma unroll
            for (int c = 0; c < 32; ++c) {
                f16x2 v = *(const f16x2*)(gp + 2 * c);
                g[2 * c]     = (float)v[0];
                g[2 * c + 1] = (float)v[1];
            }
            float pr[32];
            pr[0] = 1.0f;
            int bse = 0;
            #pragma unroll
            for (int lvl = 0; lvl < 5; ++lvl) {
                const int width = 1 << lvl;
                #pragma unroll
                for (int i = width - 1; i >= 0; --i) {
                    float p = pr[i], s = g[bse + i];
                    pr[2 * i]     = p * s;
                    pr[2 * i + 1] = p * (1.0f - s);
                }
                bse += width;
            }
            #pragma unroll
            for (int i = 0; i < 32; ++i) {
                float s5 = g[31 + i];
                float p  = pr[i];
                ov[i >> 2][(i & 3) * 2]     = (f16)(p * s5);
                ov[i >> 2][(i & 3) * 2 + 1] = (f16)(p * (1.0f - s5));
            }
        }
        __syncthreads();   // all gate reads done before overwrite

        // ---- write prob A-tiles (chunk format) over the C-tile region
        #pragma unroll
        for (int g2 = 0; g2 < 8; ++g2)
            *(f16x8*)&SH[16384 + ftr * 8192 + sw_off(frow, g2)] = ov[g2];
        __syncthreads();   // A visible; barrier also drains vmcnt -> leaf B staged

        // ---- leaf partial GEMM: lacc += prob(128x128) * Wl^T(128x128)
        #pragma unroll
        for (int ks2 = 0; ks2 < 4; ++ks2) {
            int h  = ks2 >> 1;
            int gg = (ks2 & 1) * 4 + (lane >> 4);
            f16x8 bfr[4];
            #pragma unroll
            for (int tn = 0; tn < 4; ++tn) {
                int o = wn * 64 + tn * 16 + (lane & 15);
                bfr[tn] = *(const f16x8*)&SH[h * 8192 + sw_off(o, gg)];
            }
            #pragma unroll
            for (int tm = 0; tm < 4; ++tm) {
                int m = wm * 64 + tm * 16 + (lane & 15);
                f16x8 afr = *(const f16x8*)&SH[16384 + h * 8192 + sw_off(m, gg)];
                #pragma unroll
                for (int tn = 0; tn < 4; ++tn)
                    lacc[tm][tn] = __builtin_amdgcn_mfma_f32_16x16x32_f16(afr, bfr[tn], lacc[tm][tn], 0, 0, 0);
            }
        }
        __syncthreads();   // leaf reads done before next tree-pair's staging
    }

    // ---- write f32 partial for this tp-group (streamed, no atomics)
    float* dst = partial + (size_t)tpg * BATCH * ODIM;
    #pragma unroll
    for (int tn = 0; tn < 4; ++tn) {
        int o = wn * 64 + tn * 16 + (lane & 15);
        #pragma unroll
        for (int tm = 0; tm < 4; ++tm) {
            #pragma unroll
            for (int r = 0; r < 4; ++r) {
                int row = row0 + wm * 64 + tm * 16 + (lane >> 4) * 4 + r;
                dst[(size_t)row * ODIM + o] = lacc[tm][tn][r];
            }
        }
    }

    // ---- last arriving tp-group for this rowblk reduces the 8 partials -> out
    __threadfence();                                   // release partial writes (device scope)
    if (tid == 0) sflag = atomicAdd(&cnt[blockIdx.x], 1);
    __syncthreads();
    if (sflag == TPG - 1) {
        __threadfence();                               // acquire other blocks' partials
        #pragma unroll
        for (int it = 0; it < 16; ++it) {
            int idx = it * 256 + tid;                  // 4096 f32x4 covering 128 rows
            int row = idx >> 5, c4 = idx & 31;
            size_t off = (size_t)(row0 + row) * ODIM + c4 * 4;
            f32x4 a = *(const f32x4*)(partial + off);
            #pragma unroll
            for (int k = 1; k < TPG; ++k)
                a += *(const f32x4*)(partial + (size_t)k * BATCH * ODIM + off);
            *(f32x4*)(outp + off) = a;
        }
    }
}

// ---------------- fallback (round-1 proven kernel) ----------------
#define ROWS 8
__global__ __launch_bounds__(256, 2)
void soft_tree_fallback(const float* __restrict__ x, const float* __restrict__ Wn,
                        const float* __restrict__ bn, const float* __restrict__ Wl,
                        float* __restrict__ out)
{
    __shared__ __half s_lds[ROWS][NODES][NTREE];
    const int lane = threadIdx.x & 63;
    const int w    = threadIdx.x >> 6;
    const long row0 = (long)blockIdx.x * ROWS;
    for (int n = w; n < NODES; n += 4) {
        const float* wp = Wn + ((long)n * FDIM) * NTREE + lane;
        const float* xp = x + row0 * FDIM;
        float acc[ROWS];
        #pragma unroll
        for (int r = 0; r < ROWS; ++r) acc[r] = 0.0f;
        #pragma unroll 8
        for (int f = 0; f < FDIM; ++f) {
            float wv = wp[(long)f * NTREE];
            #pragma unroll
            for (int r = 0; r < ROWS; ++r)
                acc[r] = fmaf(xp[r * FDIM + f], wv, acc[r]);
        }
        float bias = bn[n * NTREE + lane];
        #pragma unroll
        for (int r = 0; r < ROWS; ++r)
            s_lds[r][n][lane] = __float2half(smooth_step_f(acc[r] + bias));
    }
    __syncthreads();
    const int r0 = w * 2, r1 = w * 2 + 1;
    float pr0[64], pr1[64];
    {
        pr0[0] = 1.0f; pr1[0] = 1.0f;
        int base = 0;
        #pragma unroll
        for (int lvl = 0; lvl < 6; ++lvl) {
            const int width = 1 << lvl;
            #pragma unroll
            for (int i = width - 1; i >= 0; --i) {
                float sa = __half2float(s_lds[r0][base + i][lane]);
                float sb = __half2float(s_lds[r1][base + i][lane]);
                float pa = pr0[i], pb = pr1[i];
                pr0[2 * i] = pa * sa; pr0[2 * i + 1] = pa * (1.0f - sa);
                pr1[2 * i] = pb * sb; pr1[2 * i + 1] = pb * (1.0f - sb);
            }
            base += width;
        }
    }
    for (int o = 0; o < ODIM; ++o) {
        const float* wlp = Wl + (long)o * NTREE + lane;
        float c0 = 0.0f, c1 = 0.0f;
        #pragma unroll
        for (int l = 0; l < 64; ++l) {
            float wv = wlp[(long)l * (ODIM * NTREE)];
            c0 = fmaf(pr0[l], wv, c0);
            c1 = fmaf(pr1[l], wv, c1);
        }
        #pragma unroll
        for (int off = 32; off > 0; off >>= 1) {
            c0 += __shfl_xor(c0, off, 64);
            c1 += __shfl_xor(c1, off, 64);
        }
        if (lane == 0) {
            out[(row0 + r0) * ODIM + o] = c0;
            out[(row0 + r1) * ODIM + o] = c1;
        }
    }
}

extern "C" void kernel_launch(void* const* d_in, const int* in_sizes, int n_in,
                              void* d_out, int out_size, void* d_ws, size_t ws_size,
                              hipStream_t stream) {
    const float* x  = (const float*)d_in[0];
    const float* Wn = (const float*)d_in[1];
    const float* bn = (const float*)d_in[2];
    const float* Wl = (const float*)d_in[3];
    float* out = (float*)d_out;

    if (ws_size < WS_NEEDED) {
        soft_tree_fallback<<<BATCH / ROWS, 256, 0, stream>>>(x, Wn, bn, Wl, out);
        return;
    }

    f16*   xh  = (f16*)((char*)d_ws + XH_OFF);
    f16*   wnh = (f16*)((char*)d_ws + WNH_OFF);
    f16*   wlt = (f16*)((char*)d_ws + WLT_OFF);
    float* ps  = (float*)((char*)d_ws + PS_OFF);
    int*   cnt = (int*)((char*)d_ws + CNT_OFF);

    prep_kernel<<<XBLK + WLBLK + 512, 256, 0, stream>>>(x, Wn, Wl, xh, wnh, wlt, cnt);
    fused_tree<<<dim3(BATCH / 128, TPG), 256, 0, stream>>>(xh, wnh, bn, wlt, ps, cnt, out);
}

// Round 14
// 149.218 us; speedup vs baseline: 1.7173x; 1.5218x over previous
//
#include <hip/hip_runtime.h>
#include <hip/hip_fp16.h>

#define BATCH 8192
#define FDIM  512
#define NTREE 64
#define NODES 63
#define ODIM  128
#define NJP   4096            // padded node-col space: c = t*64 + n (n=63 pad)
#define K2    4096            // leaf K: k = t*64 + l
#define TPG   8               // tree-pair groups (grid.y); 4 tree-pairs each

typedef _Float16 f16;
typedef _Float16 f16x2 __attribute__((ext_vector_type(2)));
typedef _Float16 f16x4 __attribute__((ext_vector_type(4)));
typedef _Float16 f16x8 __attribute__((ext_vector_type(8)));
typedef float    f32x4 __attribute__((ext_vector_type(4)));

// ---------------- workspace layout (bytes) ----------------
#define XH_OFF   0
#define XH_SZ    ((size_t)BATCH*FDIM*2)        // 8.39 MB  x  f16 [b][f]
#define WNH_OFF  (XH_OFF + XH_SZ)
#define WNH_SZ   ((size_t)NJP*FDIM*2)          // 4.19 MB  Wn f16 [t*64+n][f]
#define WLT_OFF  (WNH_OFF + WNH_SZ)
#define WLT_SZ   ((size_t)ODIM*K2*2)           // 1.05 MB  Wl f16 [o][t*64+l]
#define PS_OFF   (WLT_OFF + WLT_SZ)
#define PS_SZ    ((size_t)TPG*BATCH*ODIM*4)    // 33.6 MB  f32 partials per tp-group
#define WS_NEEDED (PS_OFF + PS_SZ)             // 47.2 MB

__device__ __forceinline__ float smooth_step_f(float t) {
    float tc = fminf(fmaxf(t, -0.5f), 0.5f);
    return fmaf(tc, fmaf(-2.0f * tc, tc, 1.5f), 0.5f);
}

__device__ __forceinline__ void async16(const void* g, void* l) {
    __builtin_amdgcn_global_load_lds((__attribute__((address_space(1))) void*)g,
                                     (__attribute__((address_space(3))) void*)l,
                                     16, 0, 0);
}

// swizzled f16 offset of (row, group g) in a [rows][64] tile staged as 1KB/8-row chunks
__device__ __forceinline__ int sw_off(int row, int g) {
    return ((row >> 3) * 512) + (((row & 7) * 8 + (g ^ (row & 7))) * 8);
}

// ---------------- prep: all conversions in ONE launch ----------------
// blocks [0,4096): x fp32->f16 ; [4096,4224): Wl transpose ; [4224,4736): Wn transpose
#define XBLK 4096
#define WLBLK 128
__global__ __launch_bounds__(256)
void prep_kernel(const float* __restrict__ x, const float* __restrict__ wn,
                 const float* __restrict__ wl,
                 f16* __restrict__ xh, f16* __restrict__ wnh, f16* __restrict__ wlt)
{
    __shared__ __align__(16) char smem[16640];
    const int bid = blockIdx.x;

    if (bid < XBLK) {
        size_t i = ((size_t)bid * 256 + threadIdx.x) * 4;
        float4 v = *(const float4*)(x + i);
        f16x4 o4 = { (f16)v.x, (f16)v.y, (f16)v.z, (f16)v.w };
        *(f16x4*)(xh + i) = o4;                // one 8-B store (was 4x 2-B)
        return;
    }
    if (bid < XBLK + WLBLK) {
        // Wl[l][o][t] fp32 -> wlt[o][t*64+l] f16 ; one block per o
        f16 (*tile)[72] = (f16(*)[72])smem;    // [t][l]
        const int o    = bid - XBLK;
        const int lane = threadIdx.x & 63;     // t on read
        const int w    = threadIdx.x >> 6;
        #pragma unroll
        for (int lc = 0; lc < 16; ++lc) {
            int l = w * 16 + lc;
            tile[lane][l] = (f16)wl[(size_t)l * (ODIM * NTREE) + o * 64 + lane];
        }
        __syncthreads();
        f16* orow = wlt + (size_t)o * K2;
        #pragma unroll
        for (int c = 0; c < 2; ++c) {
            int idx = (threadIdx.x * 2 + c) * 8;
            int t = idx >> 6, l = idx & 63;
            f16x8 v;
            #pragma unroll
            for (int e = 0; e < 8; ++e) v[e] = tile[t][l + e];
            *(f16x8*)(orow + idx) = v;
        }
        return;
    }
    // Wn[n][f][t] fp32 -> wnh[(t*64+n)][f] f16 ; n==63 zeros pad rows
    {
        const int id   = bid - (XBLK + WLBLK);   // 0..511
        const int n    = id & 63;                // 0..63 (63 = pad)
        const int f0   = (id >> 6) * 64;         // 8 f-tiles
        const int lane = threadIdx.x & 63;
        const int w    = threadIdx.x >> 6;
        if (n == NODES) {
            #pragma unroll
            for (int tc = 0; tc < 16; ++tc) {
                int t = w * 16 + tc;
                wnh[(size_t)(t * 64 + NODES) * FDIM + f0 + lane] = (f16)0.0f;
            }
            return;
        }
        float (*tile)[65] = (float(*)[65])smem;
        const float* src = wn + (size_t)n * (FDIM * NTREE);
        #pragma unroll
        for (int i = 0; i < 16; ++i) {
            int fl = w * 16 + i;
            tile[fl][lane] = src[(size_t)(f0 + fl) * NTREE + lane];
        }
        __syncthreads();
        #pragma unroll
        for (int i = 0; i < 16; ++i) {
            int t = w * 16 + i;
            wnh[(size_t)(t * 64 + n) * FDIM + f0 + lane] = (f16)tile[lane][t];
        }
    }
}

// ---------------- fused: node GEMM (BK=64) + smooth_step + fold + leaf GEMM (per tree) ----
// grid (64 rowblks, 8 tpgroups); each block: 4 tree-pairs sequentially, lacc persistent.
// LDS = 33,280 B only -> 4 blocks/CU at VGPR<=128.
// Per tree-pair phases (f16 idx):
//   node loop : A staging [0,8192), B staging [8192,16384)
//   epilogue  : gate C-tile [0,16640) stride 130 (overlays dead staging)
//   per tree h: prob A half [0,8192) ; leaf B half [8192,16384) (overlay CT after fold)
__global__ __launch_bounds__(256, 2)
void fused_tree(const f16* __restrict__ xh, const f16* __restrict__ wnh,
                const float* __restrict__ bn, const f16* __restrict__ wlt,
                float* __restrict__ partial)
{
    __shared__ f16 SH[16640];             // 33,280 B
    const int tid  = threadIdx.x;
    const int lane = tid & 63;
    const int w    = tid >> 6;
    const int wm   = w & 1;
    const int wn   = w >> 1;
    const int row0 = blockIdx.x * 128;
    const int tpg  = blockIdx.y;

    const int lr = lane >> 3;
    const int lg = (lane & 7) ^ lr;
    const int frow = tid & 127;           // fold: row
    const int ftr  = tid >> 7;            // fold: tree within pair (0/1)

    f32x4 lacc[4][4] = {};                // leaf accumulator, persists over tree-pairs

    for (int tpi = 0; tpi < 4; ++tpi) {
        const int tp = tpg * 4 + tpi;
        const int j0 = tp * 128;          // node-col base (2 trees)

        // ---- node GEMM: 128 rows x 128 cols x K=512, BK=64 (proven round-11 loop) ----
        f32x4 acc[4][4] = {};
        for (int k0 = 0; k0 < FDIM; k0 += 64) {
            #pragma unroll
            for (int q = 0; q < 8; ++q) {
                int id = w * 8 + q;
                if (id < 16) {
                    int r = id * 8 + lr;
                    async16(xh + (size_t)(row0 + r) * FDIM + k0 + lg * 8, &SH[id * 512 + lane * 8]);
                } else {
                    int c = id - 16;
                    int r = c * 8 + lr;
                    async16(wnh + (size_t)(j0 + r) * FDIM + k0 + lg * 8, &SH[8192 + c * 512 + lane * 8]);
                }
            }
            __syncthreads();
            #pragma unroll
            for (int ks = 0; ks < 2; ++ks) {
                int g = ks * 4 + (lane >> 4);
                f16x8 bfr[4];
                #pragma unroll
                for (int tn = 0; tn < 4; ++tn) {
                    int j = wn * 64 + tn * 16 + (lane & 15);
                    bfr[tn] = *(const f16x8*)&SH[8192 + sw_off(j, g)];
                }
                #pragma unroll
                for (int tm = 0; tm < 4; ++tm) {
                    int m = wm * 64 + tm * 16 + (lane & 15);
                    f16x8 afr = *(const f16x8*)&SH[sw_off(m, g)];
                    #pragma unroll
                    for (int tn = 0; tn < 4; ++tn)
                        acc[tm][tn] = __builtin_amdgcn_mfma_f32_16x16x32_f16(afr, bfr[tn], acc[tm][tn], 0, 0, 0);
                }
            }
            __syncthreads();
        }

        // ---- gate epilogue: bias + smooth_step -> C-tile [row][130] (overlays staging)
        #pragma unroll
        for (int tn = 0; tn < 4; ++tn) {
            int col = wn * 64 + tn * 16 + (lane & 15);
            int nn  = col & 63;                       // node index (j0 multiple of 64)
            int tt  = (j0 + col) >> 6;                // global tree
            float bias = (nn < NODES) ? bn[nn * NTREE + tt] : 0.0f;
            #pragma unroll
            for (int tm = 0; tm < 4; ++tm) {
                #pragma unroll
                for (int r = 0; r < 4; ++r) {
                    int row = wm * 64 + tm * 16 + (lane >> 4) * 4 + r;
                    SH[row * 130 + col] = (f16)smooth_step_f(acc[tm][tn][r] + bias);
                }
            }
        }
        __syncthreads();

        // ---- fold: thread = (frow, ftr). gates contiguous, 2-way-free ds_read_b32
        f16x8 ov[8];
        {
            const f16* gp = &SH[frow * 130 + ftr * 64];
            float g[64];
            #pragma unroll
            for (int c = 0; c < 32; ++c) {
                f16x2 v = *(const f16x2*)(gp + 2 * c);
                g[2 * c]     = (float)v[0];
                g[2 * c + 1] = (float)v[1];
            }
            float pr[32];
            pr[0] = 1.0f;
            int bse = 0;
            #pragma unroll
            for (int lvl = 0; lvl < 5; ++lvl) {
                const int width = 1 << lvl;
                #pragma unroll
                for (int i = width - 1; i >= 0; --i) {
                    float p = pr[i], s = g[bse + i];
                    pr[2 * i]     = p * s;
                    pr[2 * i + 1] = p * (1.0f - s);
                }
                bse += width;
            }
            #pragma unroll
            for (int i = 0; i < 32; ++i) {
                float s5 = g[31 + i];
                float p  = pr[i];
                ov[i >> 2][(i & 3) * 2]     = (f16)(p * s5);
                ov[i >> 2][(i & 3) * 2 + 1] = (f16)(p * (1.0f - s5));
            }
        }
        __syncthreads();   // all gate reads done before overwrite

        // ---- leaf GEMM, one tree (64-k half) at a time: LDS stays 32 KB total ----
        #pragma unroll
        for (int h = 0; h < 2; ++h) {
            // prob A half: written by the 128 threads owning tree h
            if (ftr == h) {
                #pragma unroll
                for (int g2 = 0; g2 < 8; ++g2)
                    *(f16x8*)&SH[sw_off(frow, g2)] = ov[g2];
            }
            // leaf B half (128 o x 64 k): 16 chunks, 4 per wave
            #pragma unroll
            for (int q = 0; q < 4; ++q) {
                int c = w * 4 + q;
                int o = c * 8 + lr;
                async16(wlt + (size_t)o * K2 + j0 + h * 64 + lg * 8,
                        &SH[8192 + c * 512 + lane * 8]);
            }
            __syncthreads();   // prob visible + vmcnt drained (leaf B staged)

            #pragma unroll
            for (int ks = 0; ks < 2; ++ks) {
                int g = ks * 4 + (lane >> 4);
                f16x8 bfr[4];
                #pragma unroll
                for (int tn = 0; tn < 4; ++tn) {
                    int o = wn * 64 + tn * 16 + (lane & 15);
                    bfr[tn] = *(const f16x8*)&SH[8192 + sw_off(o, g)];
                }
                #pragma unroll
                for (int tm = 0; tm < 4; ++tm) {
                    int m = wm * 64 + tm * 16 + (lane & 15);
                    f16x8 afr = *(const f16x8*)&SH[sw_off(m, g)];
                    #pragma unroll
                    for (int tn = 0; tn < 4; ++tn)
                        lacc[tm][tn] = __builtin_amdgcn_mfma_f32_16x16x32_f16(afr, bfr[tn], lacc[tm][tn], 0, 0, 0);
                }
            }
            __syncthreads();   // reads done before next phase overwrites
        }
    }

    // ---- write f32 partial for this tp-group (streamed, no atomics, no fences)
    float* dst = partial + (size_t)tpg * BATCH * ODIM;
    #pragma unroll
    for (int tn = 0; tn < 4; ++tn) {
        int o = wn * 64 + tn * 16 + (lane & 15);
        #pragma unroll
        for (int tm = 0; tm < 4; ++tm) {
            #pragma unroll
            for (int r = 0; r < 4; ++r) {
                int row = row0 + wm * 64 + tm * 16 + (lane >> 4) * 4 + r;
                dst[(size_t)row * ODIM + o] = lacc[tm][tn][r];
            }
        }
    }
}

// ---------------- split reduce over TPG partials (separate kernel — no fences needed) ----
__global__ void reduce_kernel(const float* __restrict__ partial, float* __restrict__ out) {
    size_t i = ((size_t)blockIdx.x * blockDim.x + threadIdx.x) * 4;
    f32x4 a = *(const f32x4*)(partial + i);
    #pragma unroll
    for (int k = 1; k < TPG; ++k)
        a += *(const f32x4*)(partial + (size_t)k * BATCH * ODIM + i);
    *(f32x4*)(out + i) = a;
}

// ---------------- fallback (round-1 proven kernel) ----------------
#define ROWS 8
__global__ __launch_bounds__(256, 2)
void soft_tree_fallback(const float* __restrict__ x, const float* __restrict__ Wn,
                        const float* __restrict__ bn, const float* __restrict__ Wl,
                        float* __restrict__ out)
{
    __shared__ __half s_lds[ROWS][NODES][NTREE];
    const int lane = threadIdx.x & 63;
    const int w    = threadIdx.x >> 6;
    const long row0 = (long)blockIdx.x * ROWS;
    for (int n = w; n < NODES; n += 4) {
        const float* wp = Wn + ((long)n * FDIM) * NTREE + lane;
        const float* xp = x + row0 * FDIM;
        float acc[ROWS];
        #pragma unroll
        for (int r = 0; r < ROWS; ++r) acc[r] = 0.0f;
        #pragma unroll 8
        for (int f = 0; f < FDIM; ++f) {
            float wv = wp[(long)f * NTREE];
            #pragma unroll
            for (int r = 0; r < ROWS; ++r)
                acc[r] = fmaf(xp[r * FDIM + f], wv, acc[r]);
        }
        float bias = bn[n * NTREE + lane];
        #pragma unroll
        for (int r = 0; r < ROWS; ++r)
            s_lds[r][n][lane] = __float2half(smooth_step_f(acc[r] + bias));
    }
    __syncthreads();
    const int r0 = w * 2, r1 = w * 2 + 1;
    float pr0[64], pr1[64];
    {
        pr0[0] = 1.0f; pr1[0] = 1.0f;
        int base = 0;
        #pragma unroll
        for (int lvl = 0; lvl < 6; ++lvl) {
            const int width = 1 << lvl;
            #pragma unroll
            for (int i = width - 1; i >= 0; --i) {
                float sa = __half2float(s_lds[r0][base + i][lane]);
                float sb = __half2float(s_lds[r1][base + i][lane]);
                float pa = pr0[i], pb = pr1[i];
                pr0[2 * i] = pa * sa; pr0[2 * i + 1] = pa * (1.0f - sa);
                pr1[2 * i] = pb * sb; pr1[2 * i + 1] = pb * (1.0f - sb);
            }
            base += width;
        }
    }
    for (int o = 0; o < ODIM; ++o) {
        const float* wlp = Wl + (long)o * NTREE + lane;
        float c0 = 0.0f, c1 = 0.0f;
        #pragma unroll
        for (int l = 0; l < 64; ++l) {
            float wv = wlp[(long)l * (ODIM * NTREE)];
            c0 = fmaf(pr0[l], wv, c0);
            c1 = fmaf(pr1[l], wv, c1);
        }
        #pragma unroll
        for (int off = 32; off > 0; off >>= 1) {
            c0 += __shfl_xor(c0, off, 64);
            c1 += __shfl_xor(c1, off, 64);
        }
        if (lane == 0) {
            out[(row0 + r0) * ODIM + o] = c0;
            out[(row0 + r1) * ODIM + o] = c1;
        }
    }
}

extern "C" void kernel_launch(void* const* d_in, const int* in_sizes, int n_in,
                              void* d_out, int out_size, void* d_ws, size_t ws_size,
                              hipStream_t stream) {
    const float* x  = (const float*)d_in[0];
    const float* Wn = (const float*)d_in[1];
    const float* bn = (const float*)d_in[2];
    const float* Wl = (const float*)d_in[3];
    float* out = (float*)d_out;

    if (ws_size < WS_NEEDED) {
        soft_tree_fallback<<<BATCH / ROWS, 256, 0, stream>>>(x, Wn, bn, Wl, out);
        return;
    }

    f16*   xh  = (f16*)((char*)d_ws + XH_OFF);
    f16*   wnh = (f16*)((char*)d_ws + WNH_OFF);
    f16*   wlt = (f16*)((char*)d_ws + WLT_OFF);
    float* ps  = (float*)((char*)d_ws + PS_OFF);

    prep_kernel<<<XBLK + WLBLK + 512, 256, 0, stream>>>(x, Wn, Wl, xh, wnh, wlt);
    fused_tree<<<dim3(BATCH / 128, TPG), 256, 0, stream>>>(xh, wnh, bn, wlt, ps);
    reduce_kernel<<<(BATCH * ODIM) / (256 * 4), 256, 0, stream>>>(ps, out);
}